// Round 5
// baseline (688.841 us; speedup 1.0000x reference)
//
#include <hip/hip_runtime.h>
#include <hip/hip_bf16.h>
#include <hip/hip_fp16.h>
#include <math.h>

#define HID 128
#define EA 16
#define BM 64            // edges per block tile
#define KP 296           // msg row stride in fp16 (592 B)
#define HP 136           // H row stride in fp16 (272 B)
#define KT1 9            // GEMM1 K-tiles (K padded 273 -> 288)
#define NC 8             // GEMM1 col blocks (128 / 16)
#define NTHREADS 256
#define NBLOCKS 1024     // 4 blocks/CU x 256 CUs, grid-stride over tiles

// workspace layout (bytes)
#define HIST_OFF   0                        // int[N] degree histogram
#define ROWPTR_OFF (256*1024)               // int[N+1]
#define WRPTR_OFF  (512*1024)               // int[N] mutable cursors
#define W1S_OFF    (768*1024)
#define W1S_ELEMS  (KT1 * NC * 64 * 8)      // 36864 fp16
#define W2S_OFF    (W1S_OFF + W1S_ELEMS * 2)
#define W2S_ELEMS  (4 * 64 * 8)             // 2048 fp16
#define SORTED_OFF (1024*1024)              // u64[E] = 8 MB  (needs E<=1M)
#define FEAT16_OFF (SORTED_OFF + 8*1024*1024)  // N*HID fp16 = 12.8 MB

typedef _Float16 half8 __attribute__((ext_vector_type(8)));
typedef _Float16 half4v __attribute__((ext_vector_type(4)));
typedef float floatx4 __attribute__((ext_vector_type(4)));
typedef unsigned long long u64;

__device__ __forceinline__ float silu_f(float x) {
    return x * (1.0f / (1.0f + __expf(-x)));
}

// ---------------------------------------------------------------------------
// Prep: swizzle W1/W2 to fp16 fragment-linear layout, convert node_feat to
// fp16, zero seg.
// ---------------------------------------------------------------------------
__global__ void prep_kernel(const float* __restrict__ W1,
                            const float* __restrict__ W2,
                            const float* __restrict__ node_feat,
                            _Float16* __restrict__ w1s,
                            _Float16* __restrict__ w2s,
                            _Float16* __restrict__ feat16,
                            float* __restrict__ seg,
                            int nf8, int nseg) {
    const int idx = blockIdx.x * NTHREADS + threadIdx.x;
    if (idx < W1S_ELEMS) {
        const int i    = idx & 7;
        const int lane = (idx >> 3) & 63;
        const int c    = (idx >> 9) & 7;
        const int kt   = idx >> 12;
        const int k    = kt * 32 + (lane >> 4) * 8 + i;
        const int n    = c * 16 + (lane & 15);
        float v = 0.0f;
        if (k < 273) {
            const int src = (k < 272) ? (k + 1) : 0;   // col-permuted: dist last
            v = W1[src * HID + n];
        }
        w1s[idx] = (_Float16)v;
    }
    if (idx < W2S_ELEMS) {
        const int i    = idx & 7;
        const int lane = (idx >> 3) & 63;
        const int kt   = idx >> 9;
        const int k    = kt * 32 + (lane >> 4) * 8 + i;
        const int n    = lane & 15;
        const float v  = (n < 3) ? W2[k * 3 + n] : 0.0f;
        w2s[idx] = (_Float16)v;
    }
    if (idx < nf8) {
        const float4* src = (const float4*)node_feat;
        const float4 a = src[2 * idx];
        const float4 b = src[2 * idx + 1];
        half8 h = { (_Float16)a.x, (_Float16)a.y, (_Float16)a.z, (_Float16)a.w,
                    (_Float16)b.x, (_Float16)b.y, (_Float16)b.z, (_Float16)b.w };
        ((half8*)feat16)[idx] = h;
    }
    if (idx < nseg) seg[idx] = 0.0f;
}

// ---------------------------------------------------------------------------
// Counting sort by destination row: histogram -> scan -> permute.
// ---------------------------------------------------------------------------
__global__ void hist_kernel(const int* __restrict__ edge_index,
                            int* __restrict__ hist, int E) {
    const int e = blockIdx.x * NTHREADS + threadIdx.x;
    if (e < E) atomicAdd(hist + edge_index[e], 1);
}

__global__ void scan_kernel(const int* __restrict__ hist,
                            int* __restrict__ rowptr,
                            int* __restrict__ wrptr, int N) {
    __shared__ int wsum[16];
    __shared__ int chunk_total;
    const int tid  = threadIdx.x;
    const int lane = tid & 63;
    const int wid  = tid >> 6;
    int off = 0;
    for (int base = 0; base < N; base += 1024) {
        const int i = base + tid;
        const int x = (i < N) ? hist[i] : 0;
        int v = x;                               // inclusive scan within wave
        #pragma unroll
        for (int d = 1; d < 64; d <<= 1) {
            const int t = __shfl_up(v, d, 64);
            if (lane >= d) v += t;
        }
        if (lane == 63) wsum[wid] = v;
        __syncthreads();
        if (tid == 0) {
            int a = 0;
            #pragma unroll
            for (int wv = 0; wv < 16; ++wv) { const int t = wsum[wv]; wsum[wv] = a; a += t; }
            chunk_total = a;
        }
        __syncthreads();
        const int excl = off + wsum[wid] + v - x;
        if (i < N) { rowptr[i] = excl; wrptr[i] = excl; }
        off += chunk_total;
        __syncthreads();                         // wsum/chunk_total reuse
    }
    if (tid == 0) rowptr[N] = off;
}

// sorted[p] packs {e:32, col:16, row:16}. Requires N <= 65536 (here N=50000).
__global__ void permute_kernel(const int* __restrict__ edge_index,
                               int* __restrict__ wrptr,
                               u64* __restrict__ sorted, int E) {
    const int e = blockIdx.x * NTHREADS + threadIdx.x;
    if (e < E) {
        const int row = edge_index[e];
        const int col = edge_index[(long)E + e];
        const int p   = atomicAdd(wrptr + row, 1);
        sorted[p] = ((u64)(unsigned)e << 32)
                  | ((u64)(unsigned short)col << 16)
                  | (u64)(unsigned short)row;
    }
}

// ---------------------------------------------------------------------------
// Fused main kernel over row-sorted edges. Register prefetch of tile t+1
// (T14 async-STAGE split); per-tile segmented scan replaces per-edge atomics.
// ---------------------------------------------------------------------------
__global__ __launch_bounds__(NTHREADS, 4)
void edge_mlp_scatter_kernel(
    const _Float16* __restrict__ feat16,   // [N][128] fp16
    const float* __restrict__ node_pos,    // [N][3]
    const float* __restrict__ edge_attr,   // [E][16]
    const float* __restrict__ b1,          // [128]
    const float* __restrict__ b2,          // [3]
    const u64*   __restrict__ sorted,      // [E] packed {e,col,row}, row-sorted
    const _Float16* __restrict__ w1s,      // swizzled fp16 W1
    const _Float16* __restrict__ w2s,      // swizzled fp16 W2
    float* __restrict__ seg,               // d_out [N][9], zeroed by prep
    int E, int ntiles)
{
    __shared__ _Float16 msg[BM][KP];       // 37888 B; aliased: H[64][HP]
    __shared__ float diffb[BM][4];
    __shared__ float wbuf[BM][3];
    __shared__ int   rowb[BM];

    const int tid  = threadIdx.x;
    const int m    = tid >> 2;      // edge within tile
    const int sub  = tid & 3;       // quarter of the msg row
    const int wave = tid >> 6;
    const int lane = tid & 63;
    const int lrow = lane & 15;
    const int g    = lane >> 4;

    // ---- staged registers for the NEXT tile ----
    int   s_row = 0, s_col = 0;
    unsigned s_e = 0;
    half8 s_fr[4], s_fc[4];
    float4 s_ea;
    float s_p0 = 0, s_p1 = 0, s_p2 = 0, s_q0 = 0, s_q1 = 0, s_q2 = 0;

    // ---- prologue: issue loads for this block's first tile ----
    {
        const long p  = (long)blockIdx.x * BM + m;
        const long pc = p < E ? p : 0;
        const u64 pk = sorted[pc];
        s_row = (int)(pk & 0xffff);
        s_col = (int)((pk >> 16) & 0xffff);
        s_e   = (unsigned)(pk >> 32);
        const half8* fr = (const half8*)(feat16 + (long)s_row * HID);
        const half8* fc = (const half8*)(feat16 + (long)s_col * HID);
        #pragma unroll
        for (int t = 0; t < 4; ++t) { s_fr[t] = fr[sub * 4 + t]; s_fc[t] = fc[sub * 4 + t]; }
        s_ea = ((const float4*)(edge_attr + (long)s_e * EA))[sub];
        if (sub == 0) {
            s_p0 = node_pos[(long)s_row * 3 + 0];
            s_p1 = node_pos[(long)s_row * 3 + 1];
            s_p2 = node_pos[(long)s_row * 3 + 2];
            s_q0 = node_pos[(long)s_col * 3 + 0];
            s_q1 = node_pos[(long)s_col * 3 + 1];
            s_q2 = node_pos[(long)s_col * 3 + 2];
        }
    }

    for (int tile = blockIdx.x; tile < ntiles; tile += NBLOCKS) {
        __syncthreads();                       // (A) prev iter's LDS consumers done

        // ---- stage write: regs -> LDS ----
        {
            _Float16* mrow = &msg[m][0];
            #pragma unroll
            for (int t = 0; t < 4; ++t) {
                *(half8*)(mrow +       sub * 32 + t * 8) = s_fr[t];
                *(half8*)(mrow + 128 + sub * 32 + t * 8) = s_fc[t];
            }
            half4v h4 = { (_Float16)s_ea.x, (_Float16)s_ea.y,
                          (_Float16)s_ea.z, (_Float16)s_ea.w };
            *(half4v*)(mrow + 256 + sub * 4) = h4;
            if (sub == 0) {
                rowb[m] = s_row;
                const float dx = s_p0 - s_q0, dy = s_p1 - s_q1, dz = s_p2 - s_q2;
                const float dist = sqrtf(dx * dx + dy * dy + dz * dz);
                diffb[m][0] = dx; diffb[m][1] = dy; diffb[m][2] = dz; diffb[m][3] = dist;
                half8 z = { (_Float16)dist, (_Float16)0.f, (_Float16)0.f, (_Float16)0.f,
                            (_Float16)0.f, (_Float16)0.f, (_Float16)0.f, (_Float16)0.f };
                *(half8*)(mrow + 272) = z;
            } else if (sub == 1) {
                half8 z = { (_Float16)0.f, (_Float16)0.f, (_Float16)0.f, (_Float16)0.f,
                            (_Float16)0.f, (_Float16)0.f, (_Float16)0.f, (_Float16)0.f };
                *(half8*)(mrow + 280) = z;
            }
        }
        __syncthreads();                       // (B) msg ready

        // ---- prefetch next tile's packed entries (hides under GEMM1) ----
        const int  nt = tile + NBLOCKS;
        const bool have_next = nt < ntiles;
        if (have_next) {
            const long p  = (long)nt * BM + m;
            const long pc = p < E ? p : 0;
            const u64 pk = sorted[pc];
            s_row = (int)(pk & 0xffff);
            s_col = (int)((pk >> 16) & 0xffff);
            s_e   = (unsigned)(pk >> 32);
        }

        // ---- GEMM1: H = msg @ W1, wave owns col-blocks {2w, 2w+1} ----
        floatx4 acc[4][2];
        #pragma unroll
        for (int rb = 0; rb < 4; ++rb) {
            acc[rb][0] = (floatx4){0.f, 0.f, 0.f, 0.f};
            acc[rb][1] = (floatx4){0.f, 0.f, 0.f, 0.f};
        }
        #pragma unroll
        for (int kt = 0; kt < KT1; ++kt) {
            const half8 bf0 = *(const half8*)(w1s + ((size_t)((kt * NC + 2 * wave + 0) * 64 + lane)) * 8);
            const half8 bf1 = *(const half8*)(w1s + ((size_t)((kt * NC + 2 * wave + 1) * 64 + lane)) * 8);
            #pragma unroll
            for (int rb = 0; rb < 4; ++rb) {
                const half8 af = *(const half8*)&msg[16 * rb + lrow][kt * 32 + g * 8];
                acc[rb][0] = __builtin_amdgcn_mfma_f32_16x16x32_f16(af, bf0, acc[rb][0], 0, 0, 0);
                acc[rb][1] = __builtin_amdgcn_mfma_f32_16x16x32_f16(af, bf1, acc[rb][1], 0, 0, 0);
            }
        }

        // ---- issue next tile's gathers; fly under phase3/GEMM2/scan ----
        if (have_next) {
            const half8* fr = (const half8*)(feat16 + (long)s_row * HID);
            const half8* fc = (const half8*)(feat16 + (long)s_col * HID);
            #pragma unroll
            for (int t = 0; t < 4; ++t) { s_fr[t] = fr[sub * 4 + t]; s_fc[t] = fc[sub * 4 + t]; }
            s_ea = ((const float4*)(edge_attr + (long)s_e * EA))[sub];
            if (sub == 0) {
                s_p0 = node_pos[(long)s_row * 3 + 0];
                s_p1 = node_pos[(long)s_row * 3 + 1];
                s_p2 = node_pos[(long)s_row * 3 + 2];
                s_q0 = node_pos[(long)s_col * 3 + 0];
                s_q1 = node_pos[(long)s_col * 3 + 1];
                s_q2 = node_pos[(long)s_col * 3 + 2];
            }
        }

        __syncthreads();                       // (C) all GEMM1 msg reads done
        // ---- phase3: bias + silu, H fp16 tile (aliases msg) ----
        {
            const int col0 = 32 * wave + lrow;
            const int col1 = col0 + 16;
            const float bb0 = b1[col0];
            const float bb1 = b1[col1];
            _Float16* Hb = &msg[0][0];
            #pragma unroll
            for (int rb = 0; rb < 4; ++rb) {
                #pragma unroll
                for (int reg = 0; reg < 4; ++reg) {
                    const int r = 16 * rb + 4 * g + reg;
                    Hb[r * HP + col0] = (_Float16)silu_f(acc[rb][0][reg] + bb0);
                    Hb[r * HP + col1] = (_Float16)silu_f(acc[rb][1][reg] + bb1);
                }
            }
        }
        __syncthreads();                       // (D)

        // ---- GEMM2: w = silu(H @ W2 + b2), wave owns row-block w ----
        {
            floatx4 acc2 = (floatx4){0.f, 0.f, 0.f, 0.f};
            const _Float16* Hb = &msg[0][0];
            #pragma unroll
            for (int kt = 0; kt < 4; ++kt) {
                const half8 af = *(const half8*)(Hb + (16 * wave + lrow) * HP + kt * 32 + g * 8);
                const half8 bf = *(const half8*)(w2s + ((size_t)(kt * 64 + lane)) * 8);
                acc2 = __builtin_amdgcn_mfma_f32_16x16x32_f16(af, bf, acc2, 0, 0, 0);
            }
            if (lrow < 3) {
                const float bb2 = b2[lrow];
                #pragma unroll
                for (int reg = 0; reg < 4; ++reg)
                    wbuf[16 * wave + 4 * g + reg][lrow] = silu_f(acc2[reg] + bb2);
            }
        }
        __syncthreads();                       // (E)

        // ---- phase5 (wave 0): SH + segmented scan by row + per-segment atomics ----
        if (tid < BM) {
            const long p = (long)tile * BM + tid;
            const bool valid = p < E;
            int rw = valid ? rowb[tid] : -1;
            float v[9];
            if (valid) {
                const float dx = diffb[tid][0], dy = diffb[tid][1], dz = diffb[tid][2];
                const float dist = diffb[tid][3];
                const float inv = 1.0f / fmaxf(dist, 1e-12f);
                const float x = dx * inv, y = dy * inv, z = dz * inv;
                const float s3 = 1.7320508075688772f;
                const float w0 = wbuf[tid][0], w1 = wbuf[tid][1], w2v = wbuf[tid][2];
                v[0] = w0;
                v[1] = x * w1; v[2] = y * w1; v[3] = z * w1;
                v[4] = s3 * x * z * w2v;
                v[5] = s3 * x * y * w2v;
                v[6] = (y * y - 0.5f * (x * x + z * z)) * w2v;
                v[7] = s3 * y * z * w2v;
                v[8] = 0.5f * s3 * (z * z - x * x) * w2v;
            } else {
                #pragma unroll
                for (int c = 0; c < 9; ++c) v[c] = 0.0f;
            }
            const int rprev = __shfl_up(rw, 1, 64);
            int fl = (lane == 0 || rw != rprev) ? 1 : 0;
            #pragma unroll
            for (int d = 1; d < 64; d <<= 1) {
                const int fo = __shfl_up(fl, d, 64);
                #pragma unroll
                for (int c = 0; c < 9; ++c) {
                    const float vo = __shfl_up(v[c], d, 64);
                    if (lane >= d && !fl) v[c] += vo;
                }
                if (lane >= d) fl |= fo;
            }
            const int rnext = __shfl_down(rw, 1, 64);
            const bool endseg = (lane == 63) || (rw != rnext);
            if (endseg && rw >= 0) {
                float* o = seg + (long)rw * 9;
                #pragma unroll
                for (int c = 0; c < 9; ++c) atomicAdd(o + c, v[c]);
            }
        }
    }
}

__global__ void finalize_kernel(float* __restrict__ out,
                                const int* __restrict__ hist, int n_out) {
    const int i = blockIdx.x * blockDim.x + threadIdx.x;
    if (i < n_out) {
        const float c = (float)hist[i / 9];
        out[i] = out[i] / fmaxf(c, 1.0f);
    }
}

extern "C" void kernel_launch(void* const* d_in, const int* in_sizes, int n_in,
                              void* d_out, int out_size, void* d_ws, size_t ws_size,
                              hipStream_t stream) {
    const float* node_feat  = (const float*)d_in[0];
    const float* node_pos   = (const float*)d_in[1];
    const float* edge_attr  = (const float*)d_in[2];
    const float* W1         = (const float*)d_in[3];
    const float* b1         = (const float*)d_in[4];
    const float* W2         = (const float*)d_in[5];
    const float* b2         = (const float*)d_in[6];
    const int*   edge_index = (const int*)d_in[7];

    const int E = in_sizes[7] / 2;          // edge_index is [2][E]
    const int N = in_sizes[1] / 3;          // node_pos is [N][3]
    const int ntiles = (E + BM - 1) / BM;

    char* ws = (char*)d_ws;
    float*    seg    = (float*)d_out;       // [N][9]
    int*      hist   = (int*)(ws + HIST_OFF);
    int*      rowptr = (int*)(ws + ROWPTR_OFF);
    int*      wrptr  = (int*)(ws + WRPTR_OFF);
    _Float16* w1s    = (_Float16*)(ws + W1S_OFF);
    _Float16* w2s    = (_Float16*)(ws + W2S_OFF);
    u64*      sorted = (u64*)(ws + SORTED_OFF);
    _Float16* feat16 = (_Float16*)(ws + FEAT16_OFF);

    hipMemsetAsync(hist, 0, (size_t)N * sizeof(int), stream);

    const int nf8 = N * HID / 8;
    int nprep = nf8 > out_size ? nf8 : out_size;
    if (nprep < W1S_ELEMS) nprep = W1S_ELEMS;
    prep_kernel<<<(nprep + NTHREADS - 1) / NTHREADS, NTHREADS, 0, stream>>>(
        W1, W2, node_feat, w1s, w2s, feat16, seg, nf8, out_size);

    hist_kernel<<<(E + NTHREADS - 1) / NTHREADS, NTHREADS, 0, stream>>>(
        edge_index, hist, E);
    scan_kernel<<<1, 1024, 0, stream>>>(hist, rowptr, wrptr, N);
    permute_kernel<<<(E + NTHREADS - 1) / NTHREADS, NTHREADS, 0, stream>>>(
        edge_index, wrptr, sorted, E);

    edge_mlp_scatter_kernel<<<NBLOCKS, NTHREADS, 0, stream>>>(
        feat16, node_pos, edge_attr, b1, b2, sorted, w1s, w2s,
        seg, E, ntiles);

    const int nfin = (out_size + 255) / 256;
    finalize_kernel<<<nfin, 256, 0, stream>>>(seg, hist, out_size);
}

// Round 6
// 464.981 us; speedup vs baseline: 1.4814x; 1.4814x over previous
//
#include <hip/hip_runtime.h>
#include <hip/hip_bf16.h>
#include <hip/hip_fp16.h>
#include <math.h>

#define HID 128
#define EA 16
#define BM 64            // edges per block tile
#define EAP 40           // ea tile row stride (halfs): 80 B, 16B-aligned
#define PQP 136          // PQ/H tile row stride (halfs): 272 B
#define FTP 136          // feat tile row stride in pq_kernel
#define KT1 9            // W1 K-tiles (K padded 273 -> 288)
#define NC 8             // col blocks (128 / 16)
#define NTHREADS 256
#define GRIDM 1536       // 6 blocks/CU x 256 CUs

// workspace layout (bytes)
#define HIST_OFF   0                        // int[N]
#define WRPTR_OFF  (256*1024)               // int[N]
#define W1S_OFF    (512*1024)
#define W1S_ELEMS  (KT1 * NC * 64 * 8)      // 36864 fp16
#define W2S_OFF    (W1S_OFF + W1S_ELEMS * 2)
#define W2S_ELEMS  (4 * 64 * 8)             // 2048 fp16
#define SORTED_OFF (1024*1024)              // u64[E] = 8 MB
#define FEAT16_OFF (SORTED_OFF + 8*1024*1024)   // N*128 fp16 = 12.8 MB
#define P_OFF      (FEAT16_OFF + 13*1024*1024)  // N*128 fp16
#define Q_OFF      (P_OFF + 13*1024*1024)       // N*128 fp16

typedef _Float16 half8 __attribute__((ext_vector_type(8)));
typedef _Float16 half4v __attribute__((ext_vector_type(4)));
typedef float floatx4 __attribute__((ext_vector_type(4)));
typedef unsigned long long u64;

__device__ __forceinline__ float silu_f(float x) {
    return x * (1.0f / (1.0f + __expf(-x)));
}

// ---------------------------------------------------------------------------
// Prep: swizzle W1/W2 fp16 fragment-linear, convert node_feat to fp16, zero seg.
// ---------------------------------------------------------------------------
__global__ void prep_kernel(const float* __restrict__ W1,
                            const float* __restrict__ W2,
                            const float* __restrict__ node_feat,
                            _Float16* __restrict__ w1s,
                            _Float16* __restrict__ w2s,
                            _Float16* __restrict__ feat16,
                            float* __restrict__ seg,
                            int nf8, int nseg) {
    const int idx = blockIdx.x * NTHREADS + threadIdx.x;
    if (idx < W1S_ELEMS) {
        const int i    = idx & 7;
        const int lane = (idx >> 3) & 63;
        const int c    = (idx >> 9) & 7;
        const int kt   = idx >> 12;
        const int k    = kt * 32 + (lane >> 4) * 8 + i;
        const int n    = c * 16 + (lane & 15);
        float v = 0.0f;
        if (k < 273) {
            const int src = (k < 272) ? (k + 1) : 0;   // col-permuted: dist last
            v = W1[src * HID + n];
        }
        w1s[idx] = (_Float16)v;
    }
    if (idx < W2S_ELEMS) {
        const int i    = idx & 7;
        const int lane = (idx >> 3) & 63;
        const int kt   = idx >> 9;
        const int k    = kt * 32 + (lane >> 4) * 8 + i;
        const int n    = lane & 15;
        const float v  = (n < 3) ? W2[k * 3 + n] : 0.0f;
        w2s[idx] = (_Float16)v;
    }
    if (idx < nf8) {
        const float4* src = (const float4*)node_feat;
        const float4 a = src[2 * idx];
        const float4 b = src[2 * idx + 1];
        half8 h = { (_Float16)a.x, (_Float16)a.y, (_Float16)a.z, (_Float16)a.w,
                    (_Float16)b.x, (_Float16)b.y, (_Float16)b.z, (_Float16)b.w };
        ((half8*)feat16)[idx] = h;
    }
    if (idx < nseg) seg[idx] = 0.0f;
}

// ---------------------------------------------------------------------------
// Node-level GEMMs: P = feat @ W1_r (w1s kt 0..3), Q = feat @ W1_c (kt 4..7).
// ---------------------------------------------------------------------------
__global__ void pq_kernel(const _Float16* __restrict__ feat16,
                          const _Float16* __restrict__ w1s,
                          _Float16* __restrict__ P,
                          _Float16* __restrict__ Q, int N) {
    __shared__ _Float16 ftile[BM][FTP];
    const int tid  = threadIdx.x;
    const int base = blockIdx.x * BM;
    const int m    = tid >> 2;
    const int sub  = tid & 3;
    const int node = base + m;
    const int ncl  = node < N ? node : 0;

    const half8* fr = (const half8*)(feat16 + (long)ncl * HID);
    #pragma unroll
    for (int t = 0; t < 4; ++t)
        *(half8*)(&ftile[m][sub * 32 + t * 8]) = fr[sub * 4 + t];
    __syncthreads();

    const int wave = tid >> 6, lane = tid & 63, lrow = lane & 15, g = lane >> 4;
    floatx4 aP[4][2], aQ[4][2];
    #pragma unroll
    for (int rb = 0; rb < 4; ++rb) {
        aP[rb][0] = (floatx4){0,0,0,0}; aP[rb][1] = (floatx4){0,0,0,0};
        aQ[rb][0] = (floatx4){0,0,0,0}; aQ[rb][1] = (floatx4){0,0,0,0};
    }
    #pragma unroll
    for (int kt = 0; kt < 4; ++kt) {
        const half8 bP0 = *(const half8*)(w1s + ((size_t)(((kt    ) * NC + 2*wave    ) * 64 + lane)) * 8);
        const half8 bP1 = *(const half8*)(w1s + ((size_t)(((kt    ) * NC + 2*wave + 1) * 64 + lane)) * 8);
        const half8 bQ0 = *(const half8*)(w1s + ((size_t)(((kt + 4) * NC + 2*wave    ) * 64 + lane)) * 8);
        const half8 bQ1 = *(const half8*)(w1s + ((size_t)(((kt + 4) * NC + 2*wave + 1) * 64 + lane)) * 8);
        #pragma unroll
        for (int rb = 0; rb < 4; ++rb) {
            const half8 af = *(const half8*)&ftile[16*rb + lrow][kt*32 + g*8];
            aP[rb][0] = __builtin_amdgcn_mfma_f32_16x16x32_f16(af, bP0, aP[rb][0], 0, 0, 0);
            aP[rb][1] = __builtin_amdgcn_mfma_f32_16x16x32_f16(af, bP1, aP[rb][1], 0, 0, 0);
            aQ[rb][0] = __builtin_amdgcn_mfma_f32_16x16x32_f16(af, bQ0, aQ[rb][0], 0, 0, 0);
            aQ[rb][1] = __builtin_amdgcn_mfma_f32_16x16x32_f16(af, bQ1, aQ[rb][1], 0, 0, 0);
        }
    }
    const int c0 = 32 * wave + lrow, c1 = c0 + 16;

    // P: fragment -> LDS -> coalesced store
    __syncthreads();
    #pragma unroll
    for (int rb = 0; rb < 4; ++rb)
        #pragma unroll
        for (int reg = 0; reg < 4; ++reg) {
            const int r = 16*rb + 4*g + reg;
            ftile[r][c0] = (_Float16)aP[rb][0][reg];
            ftile[r][c1] = (_Float16)aP[rb][1][reg];
        }
    __syncthreads();
    if (node < N) {
        #pragma unroll
        for (int t = 0; t < 4; ++t)
            *(half8*)(P + (long)node * HID + sub * 32 + t * 8) = *(half8*)&ftile[m][sub*32 + t*8];
    }
    // Q
    __syncthreads();
    #pragma unroll
    for (int rb = 0; rb < 4; ++rb)
        #pragma unroll
        for (int reg = 0; reg < 4; ++reg) {
            const int r = 16*rb + 4*g + reg;
            ftile[r][c0] = (_Float16)aQ[rb][0][reg];
            ftile[r][c1] = (_Float16)aQ[rb][1][reg];
        }
    __syncthreads();
    if (node < N) {
        #pragma unroll
        for (int t = 0; t < 4; ++t)
            *(half8*)(Q + (long)node * HID + sub * 32 + t * 8) = *(half8*)&ftile[m][sub*32 + t*8];
    }
}

// ---------------------------------------------------------------------------
// Counting sort by destination row.
// ---------------------------------------------------------------------------
__global__ void hist_kernel(const int* __restrict__ edge_index,
                            int* __restrict__ hist, int E) {
    const int e = blockIdx.x * NTHREADS + threadIdx.x;
    if (e < E) atomicAdd(hist + edge_index[e], 1);
}

// single block, 1024 threads, serial chunk per thread (2 barriers total)
__global__ void scan_kernel(const int* __restrict__ hist,
                            int* __restrict__ wrptr, int N) {
    __shared__ int wsum[16];
    const int tid  = threadIdx.x;
    const int C    = (N + 1023) >> 10;
    int lo = tid * C; if (lo > N) lo = N;
    int hi = lo + C;  if (hi > N) hi = N;
    int s = 0;
    for (int i = lo; i < hi; ++i) s += hist[i];
    const int lane = tid & 63, wid = tid >> 6;
    int v = s;
    #pragma unroll
    for (int d = 1; d < 64; d <<= 1) {
        const int t = __shfl_up(v, d, 64);
        if (lane >= d) v += t;
    }
    if (lane == 63) wsum[wid] = v;
    __syncthreads();
    if (tid == 0) {
        int a = 0;
        #pragma unroll
        for (int w = 0; w < 16; ++w) { const int t = wsum[w]; wsum[w] = a; a += t; }
    }
    __syncthreads();
    int run = wsum[wid] + v - s;
    for (int i = lo; i < hi; ++i) { wrptr[i] = run; run += hist[i]; }
}

// sorted[p] packs {e:32, col:16, row:16}. Requires N <= 65536.
__global__ void permute_kernel(const int* __restrict__ edge_index,
                               int* __restrict__ wrptr,
                               u64* __restrict__ sorted, int E) {
    const int e = blockIdx.x * NTHREADS + threadIdx.x;
    if (e < E) {
        const int row = edge_index[e];
        const int col = edge_index[(long)E + e];
        const int p   = atomicAdd(wrptr + row, 1);
        sorted[p] = ((u64)(unsigned)e << 32)
                  | ((u64)(unsigned short)col << 16)
                  | (u64)(unsigned short)row;
    }
}

// ---------------------------------------------------------------------------
// Fused edge kernel over row-sorted edges. Per tile: gather PQ = P[row]+Q[col]
// into LDS, one K-tile MFMA for {ea,dist}@W1e, epilogue h=silu(acc+PQ+b1)
// in place, GEMM2, SH + segmented-scan scatter.
// ---------------------------------------------------------------------------
__global__ __launch_bounds__(NTHREADS, 6)
void edge_kernel(
    const _Float16* __restrict__ Pp,       // [N][128] fp16
    const _Float16* __restrict__ Qp,       // [N][128] fp16
    const float* __restrict__ node_pos,    // [N][3]
    const float* __restrict__ edge_attr,   // [E][16]
    const float* __restrict__ b1,          // [128]
    const float* __restrict__ b2,          // [3]
    const u64*   __restrict__ sorted,      // [E] packed {e,col,row}
    const _Float16* __restrict__ w1s,
    const _Float16* __restrict__ w2s,
    float* __restrict__ seg,               // d_out [N][9]
    int E, int ntiles)
{
    __shared__ _Float16 eat[BM][EAP];      // 5120 B: cols 0..15 ea, 16 dist, 17..31 zero
    __shared__ _Float16 pq[BM][PQP];       // 17408 B: PQ sum, then H in place
    __shared__ float diffb[BM][4];
    __shared__ float wbuf[BM][3];
    __shared__ int   rowb[BM];

    const int tid  = threadIdx.x;
    const int m    = tid >> 2;
    const int sub  = tid & 3;
    const int wave = tid >> 6;
    const int lane = tid & 63;
    const int lrow = lane & 15;
    const int g    = lane >> 4;

    // hoisted GEMM1 B-fragments (kt = 8: {ea, dist, 0-pad} block of W1)
    const half8 bW0 = *(const half8*)(w1s + ((size_t)((8 * NC + 2*wave    ) * 64 + lane)) * 8);
    const half8 bW1 = *(const half8*)(w1s + ((size_t)((8 * NC + 2*wave + 1) * 64 + lane)) * 8);
    const int col0 = 32 * wave + lrow, col1 = col0 + 16;
    const float bb0 = b1[col0], bb1 = b1[col1];

    for (int tile = blockIdx.x; tile < ntiles; tile += GRIDM) {
        __syncthreads();                       // (A) prev tile consumers done

        // ---- staging: PQ gather-sum, ea, pos ----
        {
            const long p  = (long)tile * BM + m;
            const long pc = p < E ? p : (long)(E - 1);
            const u64 pk  = sorted[pc];
            const int row = (int)(pk & 0xffff);
            const int cn  = (int)((pk >> 16) & 0xffff);
            const unsigned e = (unsigned)(pk >> 32);

            const half8* Pr = (const half8*)(Pp + (long)row * HID);
            const half8* Qc = (const half8*)(Qp + (long)cn * HID);
            #pragma unroll
            for (int t = 0; t < 4; ++t) {
                const half8 a = Pr[sub * 4 + t];
                const half8 b = Qc[sub * 4 + t];
                half8 r;
                #pragma unroll
                for (int j = 0; j < 8; ++j)
                    r[j] = (_Float16)((float)a[j] + (float)b[j]);
                *(half8*)(&pq[m][sub * 32 + t * 8]) = r;
            }
            const float4 ea = ((const float4*)(edge_attr + (long)e * EA))[sub];
            half4v h4 = { (_Float16)ea.x, (_Float16)ea.y, (_Float16)ea.z, (_Float16)ea.w };
            *(half4v*)(&eat[m][sub * 4]) = h4;
            if (sub == 0) {
                rowb[m] = row;
                const float dx = node_pos[row*3+0] - node_pos[cn*3+0];
                const float dy = node_pos[row*3+1] - node_pos[cn*3+1];
                const float dz = node_pos[row*3+2] - node_pos[cn*3+2];
                const float dist = sqrtf(dx*dx + dy*dy + dz*dz);
                diffb[m][0] = dx; diffb[m][1] = dy; diffb[m][2] = dz; diffb[m][3] = dist;
                half8 z = { (_Float16)dist, (_Float16)0.f, (_Float16)0.f, (_Float16)0.f,
                            (_Float16)0.f, (_Float16)0.f, (_Float16)0.f, (_Float16)0.f };
                *(half8*)(&eat[m][16]) = z;
            } else if (sub == 1) {
                half8 z = { (_Float16)0.f, (_Float16)0.f, (_Float16)0.f, (_Float16)0.f,
                            (_Float16)0.f, (_Float16)0.f, (_Float16)0.f, (_Float16)0.f };
                *(half8*)(&eat[m][24]) = z;
            }
        }
        __syncthreads();                       // (B) tiles ready

        // ---- GEMM1: {ea,dist} @ W1e — 8 MFMAs ----
        floatx4 acc[4][2];
        #pragma unroll
        for (int rb = 0; rb < 4; ++rb) {
            acc[rb][0] = (floatx4){0,0,0,0};
            acc[rb][1] = (floatx4){0,0,0,0};
        }
        #pragma unroll
        for (int rb = 0; rb < 4; ++rb) {
            const half8 af = *(const half8*)&eat[16*rb + lrow][g * 8];
            acc[rb][0] = __builtin_amdgcn_mfma_f32_16x16x32_f16(af, bW0, acc[rb][0], 0, 0, 0);
            acc[rb][1] = __builtin_amdgcn_mfma_f32_16x16x32_f16(af, bW1, acc[rb][1], 0, 0, 0);
        }

        // ---- epilogue: h = silu(acc + PQ + b1), H written in place ----
        #pragma unroll
        for (int rb = 0; rb < 4; ++rb)
            #pragma unroll
            for (int reg = 0; reg < 4; ++reg) {
                const int r = 16*rb + 4*g + reg;
                const float h0 = silu_f(acc[rb][0][reg] + (float)pq[r][col0] + bb0);
                const float h1 = silu_f(acc[rb][1][reg] + (float)pq[r][col1] + bb1);
                pq[r][col0] = (_Float16)h0;
                pq[r][col1] = (_Float16)h1;
            }
        __syncthreads();                       // (D) H complete

        // ---- GEMM2: w = silu(H @ W2 + b2) ----
        {
            floatx4 acc2 = (floatx4){0,0,0,0};
            #pragma unroll
            for (int kt = 0; kt < 4; ++kt) {
                const half8 af = *(const half8*)&pq[16*wave + lrow][kt*32 + g*8];
                const half8 bf = *(const half8*)(w2s + ((size_t)(kt * 64 + lane)) * 8);
                acc2 = __builtin_amdgcn_mfma_f32_16x16x32_f16(af, bf, acc2, 0, 0, 0);
            }
            if (lrow < 3) {
                const float bb2 = b2[lrow];
                #pragma unroll
                for (int reg = 0; reg < 4; ++reg)
                    wbuf[16*wave + 4*g + reg][lrow] = silu_f(acc2[reg] + bb2);
            }
        }
        __syncthreads();                       // (E)

        // ---- SH + segmented scan by row + per-segment atomics (wave 0) ----
        if (tid < BM) {
            const long p = (long)tile * BM + tid;
            const bool valid = p < E;
            int rw = valid ? rowb[tid] : -1;
            float v[9];
            if (valid) {
                const float dx = diffb[tid][0], dy = diffb[tid][1], dz = diffb[tid][2];
                const float dist = diffb[tid][3];
                const float inv = 1.0f / fmaxf(dist, 1e-12f);
                const float x = dx * inv, y = dy * inv, z = dz * inv;
                const float s3 = 1.7320508075688772f;
                const float w0 = wbuf[tid][0], w1 = wbuf[tid][1], w2v = wbuf[tid][2];
                v[0] = w0;
                v[1] = x * w1; v[2] = y * w1; v[3] = z * w1;
                v[4] = s3 * x * z * w2v;
                v[5] = s3 * x * y * w2v;
                v[6] = (y * y - 0.5f * (x * x + z * z)) * w2v;
                v[7] = s3 * y * z * w2v;
                v[8] = 0.5f * s3 * (z * z - x * x) * w2v;
            } else {
                #pragma unroll
                for (int c = 0; c < 9; ++c) v[c] = 0.0f;
            }
            const int rprev = __shfl_up(rw, 1, 64);
            int fl = (tid == 0 || rw != rprev) ? 1 : 0;
            #pragma unroll
            for (int d = 1; d < 64; d <<= 1) {
                const int fo = __shfl_up(fl, d, 64);
                #pragma unroll
                for (int c = 0; c < 9; ++c) {
                    const float vo = __shfl_up(v[c], d, 64);
                    if (tid >= d && !fl) v[c] += vo;
                }
                if (tid >= d) fl |= fo;
            }
            const int rnext = __shfl_down(rw, 1, 64);
            const bool endseg = (tid == 63) || (rw != rnext);
            if (endseg && rw >= 0) {
                float* o = seg + (long)rw * 9;
                #pragma unroll
                for (int c = 0; c < 9; ++c) atomicAdd(o + c, v[c]);
            }
        }
    }
}

__global__ void finalize_kernel(float* __restrict__ out,
                                const int* __restrict__ hist, int n_out) {
    const int i = blockIdx.x * blockDim.x + threadIdx.x;
    if (i < n_out) {
        const float c = (float)hist[i / 9];
        out[i] = out[i] / fmaxf(c, 1.0f);
    }
}

extern "C" void kernel_launch(void* const* d_in, const int* in_sizes, int n_in,
                              void* d_out, int out_size, void* d_ws, size_t ws_size,
                              hipStream_t stream) {
    const float* node_feat  = (const float*)d_in[0];
    const float* node_pos   = (const float*)d_in[1];
    const float* edge_attr  = (const float*)d_in[2];
    const float* W1         = (const float*)d_in[3];
    const float* b1         = (const float*)d_in[4];
    const float* W2         = (const float*)d_in[5];
    const float* b2         = (const float*)d_in[6];
    const int*   edge_index = (const int*)d_in[7];

    const int E = in_sizes[7] / 2;
    const int N = in_sizes[1] / 3;
    const int ntiles = (E + BM - 1) / BM;

    char* ws = (char*)d_ws;
    float*    seg    = (float*)d_out;
    int*      hist   = (int*)(ws + HIST_OFF);
    int*      wrptr  = (int*)(ws + WRPTR_OFF);
    _Float16* w1s    = (_Float16*)(ws + W1S_OFF);
    _Float16* w2s    = (_Float16*)(ws + W2S_OFF);
    u64*      sorted = (u64*)(ws + SORTED_OFF);
    _Float16* feat16 = (_Float16*)(ws + FEAT16_OFF);
    _Float16* Pp     = (_Float16*)(ws + P_OFF);
    _Float16* Qp     = (_Float16*)(ws + Q_OFF);

    hipMemsetAsync(hist, 0, (size_t)N * sizeof(int), stream);

    const int nf8 = N * HID / 8;
    int nprep = nf8 > out_size ? nf8 : out_size;
    if (nprep < W1S_ELEMS) nprep = W1S_ELEMS;
    prep_kernel<<<(nprep + NTHREADS - 1) / NTHREADS, NTHREADS, 0, stream>>>(
        W1, W2, node_feat, w1s, w2s, feat16, seg, nf8, out_size);

    hist_kernel<<<(E + NTHREADS - 1) / NTHREADS, NTHREADS, 0, stream>>>(
        edge_index, hist, E);
    scan_kernel<<<1, 1024, 0, stream>>>(hist, wrptr, N);
    permute_kernel<<<(E + NTHREADS - 1) / NTHREADS, NTHREADS, 0, stream>>>(
        edge_index, wrptr, sorted, E);

    pq_kernel<<<(N + BM - 1) / BM, NTHREADS, 0, stream>>>(feat16, w1s, Pp, Qp, N);

    edge_kernel<<<GRIDM, NTHREADS, 0, stream>>>(
        Pp, Qp, node_pos, edge_attr, b1, b2, sorted, w1s, w2s, seg, E, ntiles);

    const int nfin = (out_size + 255) / 256;
    finalize_kernel<<<nfin, 256, 0, stream>>>(seg, hist, out_size);
}